// Round 8
// baseline (799.411 us; speedup 1.0000x reference)
//
#include <hip/hip_runtime.h>
#include <stdint.h>

#define XDIM 131
#define LATENT 128
#define GSZ 513
#define FEAT0 136            // feats occupy cols 136..231; W0 rows permuted to match
#define TROWS 64             // points per tile
#define BSTRIDE 1040         // bytes per c-block: 64 rows * 16B + 16B pad
#define NBLK 512             // persistent grid (2 blocks/CU)

typedef __attribute__((ext_vector_type(8))) short bf16x8;
typedef __attribute__((ext_vector_type(4))) short bf16x4;
typedef __attribute__((ext_vector_type(4))) float f32x4;
typedef unsigned int uint32;

__device__ __forceinline__ unsigned short f2bf(float f) {
  uint32 u = __float_as_uint(f);
  u += 0x7fffu + ((u >> 16) & 1u);   // RTNE
  return (unsigned short)(u >> 16);
}
__device__ __forceinline__ float bf2f(unsigned short s) {
  return __uint_as_float(((uint32)s) << 16);
}
__device__ __forceinline__ uint32 pk2bf(float a, float b) {
  return (uint32)f2bf(a) | ((uint32)f2bf(b) << 16);
}

__device__ __forceinline__ int slot16(int r) { return (r * 16) ^ (((r >> 3) & 1) << 5); }
__device__ __forceinline__ int blk_of(int c) { return (c >> 5) * 4 + ((c >> 3) & 3); }

// ---------------- prep: P [3][32][513][513] f32 -> Pt [3][513][513][32] bf16
__global__ void prep_pt(const float* __restrict__ P, unsigned short* __restrict__ Pt) {
  int i = blockIdx.x * 256 + threadIdx.x;
  const int CELLS = 3 * GSZ * GSZ;
  if (i >= CELLS) return;
  int pl = i / (GSZ * GSZ);
  int yx = i - pl * (GSZ * GSZ);
  const float* src = P + (size_t)pl * 32 * GSZ * GSZ + yx;
  const size_t GG = (size_t)GSZ * GSZ;
  uint4* dst = (uint4*)(Pt + (size_t)i * 32);
#pragma unroll
  for (int w = 0; w < 4; ++w) {
    uint4 t;
    t.x = pk2bf(src[(w * 8 + 0) * GG], src[(w * 8 + 1) * GG]);
    t.y = pk2bf(src[(w * 8 + 2) * GG], src[(w * 8 + 3) * GG]);
    t.z = pk2bf(src[(w * 8 + 4) * GG], src[(w * 8 + 5) * GG]);
    t.w = pk2bf(src[(w * 8 + 6) * GG], src[(w * 8 + 7) * GG]);
    dst[w] = t;
  }
}

// ---------------- prep: W0/W1 -> bf16 MFMA B-frag order [kb][g][n][8], W0 K-permuted
__global__ void prep_w(const float* __restrict__ W0, const float* __restrict__ W1,
                       unsigned short* __restrict__ W0g, unsigned short* __restrict__ W1g) {
  int i = blockIdx.x * 256 + threadIdx.x;  // 0..16383
  int sel = i >> 13;
  int t = i & 8191;
  int kb = t >> 10;
  int g  = (t >> 8) & 3;
  int n  = t & 255;
  float vv[8];
#pragma unroll
  for (int j = 0; j < 8; ++j) {
    int k = kb * 32 + g * 8 + j;
    float val;
    if (sel == 0) {
      int src = (k < 131) ? k : ((k >= FEAT0 && k < FEAT0 + 96) ? k - 5 : -1);
      val = (src >= 0) ? W0[src * 256 + n] : 0.f;
    } else {
      val = W1[k * 256 + n];
    }
    vv[j] = val;
  }
  uint4 o;
  o.x = pk2bf(vv[0], vv[1]);
  o.y = pk2bf(vv[2], vv[3]);
  o.z = pk2bf(vv[4], vv[5]);
  o.w = pk2bf(vv[6], vv[7]);
  unsigned short* dst = (sel == 0 ? W0g : W1g) + (size_t)t * 8;
  *(uint4*)dst = o;
}

// 8-wave GEMM: tile 64 rows x 256 cols; wave cg owns cols [cg*32, cg*32+32).
__device__ __forceinline__ void gemm_layer(unsigned char* actb,
                                           const unsigned short* __restrict__ Wg,
                                           const float* __restrict__ bias,
                                           int cg, int lr, int lg)
{
  f32x4 acc[4][2];
#pragma unroll
  for (int mf = 0; mf < 4; ++mf)
#pragma unroll
    for (int nf = 0; nf < 2; ++nf) acc[mf][nf] = (f32x4){0.f, 0.f, 0.f, 0.f};

#pragma unroll
  for (int kb = 0; kb < 8; ++kb) {
    bf16x8 a[4];
    const int ab = (kb * 4 + lg) * BSTRIDE;
#pragma unroll
    for (int mf = 0; mf < 4; ++mf)
      a[mf] = *(const bf16x8*)(actb + ab + slot16(mf * 16 + lr));
    const unsigned short* wb = Wg + (size_t)(kb * 4 + lg) * 2048 + (size_t)(cg * 32 + lr) * 8;
#pragma unroll
    for (int nf = 0; nf < 2; ++nf) {
      bf16x8 b = *(const bf16x8*)(wb + nf * 128);
#pragma unroll
      for (int mf = 0; mf < 4; ++mf)
        acc[mf][nf] = __builtin_amdgcn_mfma_f32_16x16x32_bf16(a[mf], b, acc[mf][nf], 0, 0, 0);
    }
  }
  float bs[2];
#pragma unroll
  for (int nf = 0; nf < 2; ++nf) bs[nf] = bias[cg * 32 + nf * 16 + lr];
  __syncthreads();   // all reads of act done before overwrite with h
#pragma unroll
  for (int mf = 0; mf < 4; ++mf)
#pragma unroll
    for (int nf = 0; nf < 2; ++nf) {
      int c = cg * 32 + nf * 16 + lr;
      unsigned char* dst = actb + blk_of(c) * BSTRIDE + (c & 7) * 2;
#pragma unroll
      for (int reg = 0; reg < 4; ++reg) {
        int r = mf * 16 + lg * 4 + reg;
        float vv = fmaxf(acc[mf][nf][reg] + bs[nf], 0.f);
        *(unsigned short*)(dst + slot16(r)) = f2bf(vv);
      }
    }
  __syncthreads();
}

// Fused, persistent, software-pipelined kernel.
// Per iteration: consume staged regs -> LDS; issue loads for tile+G; GEMMs; epilogue.
template<int USE_PT>
__global__ __launch_bounds__(512, 4) void sdf_fused(
    const float* __restrict__ x, const float* __restrict__ P,
    const unsigned short* __restrict__ Pt,
    const unsigned short* __restrict__ W0g, const unsigned short* __restrict__ W1g,
    const float* __restrict__ b0, const float* __restrict__ b1,
    const float* __restrict__ W2, const float* __restrict__ b2v,
    float* __restrict__ out, int Npts, int ntiles)
{
  __shared__ __align__(16) unsigned char actb[32 * BSTRIDE];   // 33280 B

  const int tid = threadIdx.x;
  const int G = gridDim.x;
  const int lane = tid & 63, cg = tid >> 6;
  const int lr = lane & 15, lg = lane >> 4;
  const int p_l8 = tid >> 3, q8 = tid & 7;     // gather/epilogue: 8 threads/point

  // ---- staged register state (live across GEMMs) ----
  float xs[16];        // 2 x-tasks x 8 cols
  float c0 = 0.f, c1 = 0.f, c2 = 0.f;
  float wxv[3], wyv[3];
  bf16x4 gv[12];       // 3 planes x 4 corners x 4 channels (USE_PT only)

  // ---- ISSUE: start all global loads for tile `t` ----
  auto ISSUE = [&](int t) {
    int pbase = t * TROWS;
#pragma unroll
    for (int k = 0; k < 2; ++k) {
      int tt = k * 512 + tid;
      int cb = tt & 15, r = tt >> 4;
      int p = min(pbase + r, Npts - 1);
      const float* src = x + (size_t)p * XDIM + cb * 8;
#pragma unroll
      for (int j = 0; j < 8; ++j) xs[k * 8 + j] = src[j];
    }
    int p = min(pbase + p_l8, Npts - 1);
    const float* xr = x + (size_t)p * XDIM + LATENT;
    c0 = xr[0]; c1 = xr[1]; c2 = xr[2];
#pragma unroll
    for (int pl = 0; pl < 3; ++pl) {
      float u = (pl == 2) ? c1 : c0;
      float v = (pl == 0) ? c1 : c2;
      float gx = fminf(fmaxf((u + 1.f) * 256.f, 0.f), 512.f);
      float gy = fminf(fmaxf((v + 1.f) * 256.f, 0.f), 512.f);
      float x0f = floorf(gx), y0f = floorf(gy);
      int x0 = (int)x0f, y0 = (int)y0f;
      int x1 = min(x0 + 1, GSZ - 1), y1 = min(y0 + 1, GSZ - 1);
      wxv[pl] = gx - x0f; wyv[pl] = gy - y0f;
      if (USE_PT) {
        const unsigned short* pb = Pt + (size_t)pl * GSZ * GSZ * 32 + q8 * 4;
        gv[pl * 4 + 0] = *(const bf16x4*)(pb + (size_t)(y0 * GSZ + x0) * 32);
        gv[pl * 4 + 1] = *(const bf16x4*)(pb + (size_t)(y0 * GSZ + x1) * 32);
        gv[pl * 4 + 2] = *(const bf16x4*)(pb + (size_t)(y1 * GSZ + x0) * 32);
        gv[pl * 4 + 3] = *(const bf16x4*)(pb + (size_t)(y1 * GSZ + x1) * 32);
      } else {
        // fallback: synchronous f32 gathers from raw P
#pragma unroll
        for (int j = 0; j < 4; ++j) {
          const float* pc = P + (size_t)(pl * 32 + q8 * 4 + j) * GSZ * GSZ;
          float w00 = (1.f - wxv[pl]) * (1.f - wyv[pl]), w01 = wxv[pl] * (1.f - wyv[pl]);
          float w10 = (1.f - wxv[pl]) * wyv[pl],         w11 = wxv[pl] * wyv[pl];
          float f = w00 * pc[y0 * GSZ + x0] + w01 * pc[y0 * GSZ + x1]
                  + w10 * pc[y1 * GSZ + x0] + w11 * pc[y1 * GSZ + x1];
          short s = (short)f2bf(f);
          bf16x4 tmp = gv[pl * 4 + j & 3];  (void)tmp;
          // store f directly into gv slot j of plane: pack later uses weights=identity
          gv[pl * 4 + 0][j] = s;            // corner0 carries final value; others unused
        }
        gv[pl * 4 + 1] = (bf16x4){0,0,0,0};
        gv[pl * 4 + 2] = (bf16x4){0,0,0,0};
        gv[pl * 4 + 3] = (bf16x4){0,0,0,0};
        wxv[pl] = 0.f; wyv[pl] = 0.f;       // w00=1 -> combine passes through
      }
    }
  };

  // ---- STAGE_WRITE: pack staged regs -> LDS, re-zero pads ----
  auto STAGE_WRITE = [&]() {
    // zero blocks 29..31 (cols 232..255): 195 uint4
    if (tid < 195) {
      uint4 zz = {0u, 0u, 0u, 0u};
      ((uint4*)(actb + 29 * BSTRIDE))[tid] = zz;
    }
    // x cols 0..127
#pragma unroll
    for (int k = 0; k < 2; ++k) {
      int tt = k * 512 + tid;
      int cb = tt & 15, r = tt >> 4;
      uint4 v;
      v.x = pk2bf(xs[k * 8 + 0], xs[k * 8 + 1]);
      v.y = pk2bf(xs[k * 8 + 2], xs[k * 8 + 3]);
      v.z = pk2bf(xs[k * 8 + 4], xs[k * 8 + 5]);
      v.w = pk2bf(xs[k * 8 + 6], xs[k * 8 + 7]);
      *(uint4*)(actb + cb * BSTRIDE + slot16(r)) = v;
    }
    // coords row (block 16): cols 128..130 + zero pad 131..135
    if (q8 == 0) {
      uint4 v;
      v.x = pk2bf(c0, c1);
      v.y = pk2bf(c2, 0.f);
      v.z = 0u; v.w = 0u;
      *(uint4*)(actb + 16 * BSTRIDE + slot16(p_l8)) = v;
    }
    // feats cols 136..231
#pragma unroll
    for (int pl = 0; pl < 3; ++pl) {
      float wx = wxv[pl], wy = wyv[pl];
      float w00 = (1.f - wx) * (1.f - wy), w01 = wx * (1.f - wy);
      float w10 = (1.f - wx) * wy,        w11 = wx * wy;
      float f[4];
#pragma unroll
      for (int j = 0; j < 4; ++j) {
        f[j] = w00 * bf2f((unsigned short)gv[pl * 4 + 0][j])
             + w01 * bf2f((unsigned short)gv[pl * 4 + 1][j])
             + w10 * bf2f((unsigned short)gv[pl * 4 + 2][j])
             + w11 * bf2f((unsigned short)gv[pl * 4 + 3][j]);
      }
      int c = FEAT0 + pl * 32 + q8 * 4;
      uint2 fv;
      fv.x = pk2bf(f[0], f[1]);
      fv.y = pk2bf(f[2], f[3]);
      *(uint2*)(actb + blk_of(c) * BSTRIDE + slot16(p_l8) + (c & 7) * 2) = fv;
    }
  };

  int tile = blockIdx.x;
  if (tile < ntiles) ISSUE(tile);

  for (; tile < ntiles; tile += G) {
    __syncthreads();            // prior epilogue reads done
    STAGE_WRITE();
    if (tile + G < ntiles) ISSUE(tile + G);   // loads in flight across GEMMs
    __syncthreads();

    gemm_layer(actb, W0g, b0, cg, lr, lg);    // layer 0 (K=256, permuted/padded)
    gemm_layer(actb, W1g, b1, cg, lr, lg);    // layer 1 (K=256)

    // ---- layer 2: h @ W2 + b2 (8 threads per point)
    {
      float sum = 0.f;
#pragma unroll
      for (int jj = 0; jj < 4; ++jj) {
        int b = q8 * 4 + jj;
        int cbase = (b >> 2) * 32 + (b & 3) * 8;
        bf16x8 h = *(const bf16x8*)(actb + b * BSTRIDE + slot16(p_l8));
        float4 wa = *(const float4*)(W2 + cbase);
        float4 wb4 = *(const float4*)(W2 + cbase + 4);
        sum += bf2f((unsigned short)h[0]) * wa.x + bf2f((unsigned short)h[1]) * wa.y
             + bf2f((unsigned short)h[2]) * wa.z + bf2f((unsigned short)h[3]) * wa.w
             + bf2f((unsigned short)h[4]) * wb4.x + bf2f((unsigned short)h[5]) * wb4.y
             + bf2f((unsigned short)h[6]) * wb4.z + bf2f((unsigned short)h[7]) * wb4.w;
      }
      sum += __shfl_xor(sum, 1);
      sum += __shfl_xor(sum, 2);
      sum += __shfl_xor(sum, 4);
      if (q8 == 0) {
        int p = tile * TROWS + p_l8;
        if (p < Npts) out[p] = sum + b2v[0];
      }
    }
  }
}

extern "C" void kernel_launch(void* const* d_in, const int* in_sizes, int n_in,
                              void* d_out, int out_size, void* d_ws, size_t ws_size,
                              hipStream_t stream)
{
  const float* x  = (const float*)d_in[0];
  const float* P  = (const float*)d_in[1];
  const float* W0 = (const float*)d_in[2];
  const float* b0 = (const float*)d_in[3];
  const float* W1 = (const float*)d_in[4];
  const float* b1 = (const float*)d_in[5];
  const float* W2 = (const float*)d_in[6];
  const float* b2 = (const float*)d_in[7];
  float* out = (float*)d_out;
  int Npts = in_sizes[0] / XDIM;
  int ntiles = (Npts + TROWS - 1) / TROWS;

  const size_t PT_BYTES = (size_t)3 * GSZ * GSZ * 32 * 2;   // ~50.5 MB
  const size_t WG_BYTES = (size_t)8192 * 8 * 2;             // 128 KB each
  char* ws = (char*)d_ws;

  int use_pt = (ws_size >= PT_BYTES + 2 * WG_BYTES) ? 1 : 0;
  unsigned short *Ptb = nullptr, *W0g, *W1g;
  if (use_pt) {
    Ptb = (unsigned short*)ws;
    W0g = (unsigned short*)(ws + PT_BYTES);
    W1g = (unsigned short*)(ws + PT_BYTES + WG_BYTES);
  } else {
    W0g = (unsigned short*)ws;
    W1g = (unsigned short*)(ws + WG_BYTES);
  }

  prep_w<<<64, 256, 0, stream>>>(W0, W1, W0g, W1g);
  if (use_pt) prep_pt<<<(3 * GSZ * GSZ + 255) / 256, 256, 0, stream>>>(P, Ptb);

  int nblk = ntiles < NBLK ? ntiles : NBLK;
  if (use_pt)
    sdf_fused<1><<<nblk, 512, 0, stream>>>(x, P, Ptb, W0g, W1g, b0, b1, W2, b2, out, Npts, ntiles);
  else
    sdf_fused<0><<<nblk, 512, 0, stream>>>(x, P, Ptb, W0g, W1g, b0, b1, W2, b2, out, Npts, ntiles);
}

// Round 9
// 408.931 us; speedup vs baseline: 1.9549x; 1.9549x over previous
//
#include <hip/hip_runtime.h>
#include <stdint.h>

#define XDIM 131
#define GSZ 513
#define TROWS 64
#define H_OFF   30720          // act: 30 k-blocks * 1024
#define SC_OFF  63488          // H: 32 blocks * 1024 = 32768 -> ends 63488
#define LDS_BYTES 64000        // + 512B scratch

typedef __attribute__((ext_vector_type(8))) short bf16x8;
typedef __attribute__((ext_vector_type(4))) float f32x4;
typedef unsigned int uint32;

__device__ __forceinline__ unsigned short f2bf(float f) {
  uint32 u = __float_as_uint(f);
  u += 0x7fffu + ((u >> 16) & 1u);   // RTNE
  return (unsigned short)(u >> 16);
}
__device__ __forceinline__ float bf2f(unsigned short s) {
  return __uint_as_float(((uint32)s) << 16);
}
__device__ __forceinline__ uint32 pk2bf(float a, float b) {
  return (uint32)f2bf(a) | ((uint32)f2bf(b) << 16);
}
__device__ __forceinline__ int slot16(int r) { return (r * 16) ^ (((r >> 3) & 1) << 5); }

// ---------------- prep: P [3][32][513][513] f32 -> Pt [3][513][513][32] bf16
__global__ void prep_pt(const float* __restrict__ P, unsigned short* __restrict__ Pt) {
  int i = blockIdx.x * 256 + threadIdx.x;
  const int CELLS = 3 * GSZ * GSZ;
  if (i >= CELLS) return;
  int pl = i / (GSZ * GSZ);
  int yx = i - pl * (GSZ * GSZ);
  const float* src = P + (size_t)pl * 32 * GSZ * GSZ + yx;
  const size_t GG = (size_t)GSZ * GSZ;
  uint4* dst = (uint4*)(Pt + (size_t)i * 32);
#pragma unroll
  for (int w = 0; w < 4; ++w) {
    uint4 t;
    t.x = pk2bf(src[(w * 8 + 0) * GG], src[(w * 8 + 1) * GG]);
    t.y = pk2bf(src[(w * 8 + 2) * GG], src[(w * 8 + 3) * GG]);
    t.z = pk2bf(src[(w * 8 + 4) * GG], src[(w * 8 + 5) * GG]);
    t.w = pk2bf(src[(w * 8 + 6) * GG], src[(w * 8 + 7) * GG]);
    dst[w] = t;
  }
}

// ---------------- prep: W0/W1 -> bf16 MFMA B-frag order [kb][lg][n][8], W0 K-permuted
__global__ void prep_w(const float* __restrict__ W0, const float* __restrict__ W1,
                       unsigned short* __restrict__ W0g, unsigned short* __restrict__ W1g) {
  int i = blockIdx.x * 256 + threadIdx.x;  // 0..16383
  int sel = i >> 13;
  int t = i & 8191;
  int kb = t >> 10;
  int g  = (t >> 8) & 3;
  int n  = t & 255;
  float vv[8];
#pragma unroll
  for (int j = 0; j < 8; ++j) {
    int k = kb * 32 + g * 8 + j;
    float val;
    if (sel == 0) {
      int src = (k < 131) ? k : ((k >= 136 && k < 232) ? k - 5 : -1);
      val = (src >= 0) ? W0[src * 256 + n] : 0.f;
    } else {
      val = W1[k * 256 + n];
    }
    vv[j] = val;
  }
  uint4 o;
  o.x = pk2bf(vv[0], vv[1]);
  o.y = pk2bf(vv[2], vv[3]);
  o.z = pk2bf(vv[4], vv[5]);
  o.w = pk2bf(vv[6], vv[7]);
  unsigned short* dst = (sel == 0 ? W0g : W1g) + (size_t)t * 8;
  *(uint4*)dst = o;
}

// One 64-pt tile per 128-thread block (2 waves). 3 barriers. No h1 writeback.
template<int USE_PT>
__global__ __launch_bounds__(128) void sdf_tile(
    const float* __restrict__ x, const float* __restrict__ P,
    const unsigned short* __restrict__ Pt,
    const unsigned short* __restrict__ W0g, const unsigned short* __restrict__ W1g,
    const float* __restrict__ b0, const float* __restrict__ b1,
    const float* __restrict__ W2, const float* __restrict__ b2v,
    float* __restrict__ out, int Npts)
{
  __shared__ __align__(16) unsigned char lds[LDS_BYTES];

  const int tid = threadIdx.x;
  const int p0 = blockIdx.x * TROWS;
  const int lane = tid & 63, wv = tid >> 6;         // 2 waves
  const int lr = lane & 15, lg = lane >> 4;

  // ---- stage x cols 0..127 (act blocks 0..15)
#pragma unroll
  for (int i = 0; i < 8; ++i) {
    int t = i * 128 + tid;
    int r = t & 63, cb = t >> 6;
    int p = min(p0 + r, Npts - 1);
    const float* src = x + (size_t)p * XDIM + cb * 8;
    uint4 v;
    v.x = pk2bf(src[0], src[1]);
    v.y = pk2bf(src[2], src[3]);
    v.z = pk2bf(src[4], src[5]);
    v.w = pk2bf(src[6], src[7]);
    *(uint4*)(lds + cb * 1024 + slot16(r)) = v;
  }
  // coords (block 16, cols 128..135 with zero pad) and zero block 29
  if (tid < 64) {
    int p = min(p0 + tid, Npts - 1);
    const float* xr = x + (size_t)p * XDIM + 128;
    uint4 v;
    v.x = pk2bf(xr[0], xr[1]);
    v.y = pk2bf(xr[2], 0.f);
    v.z = 0u; v.w = 0u;
    *(uint4*)(lds + 16 * 1024 + slot16(tid)) = v;
  } else {
    uint4 z = {0u, 0u, 0u, 0u};
    ((uint4*)(lds + 29 * 1024))[tid - 64] = z;      // 64 uint4 = 1024 B
  }

  // ---- fused triplane gather -> act blocks 17..28 (cols 136..231)
#pragma unroll
  for (int g = 0; g < 2; ++g) {
    int pt = g * 32 + (tid >> 2);
    int q = tid & 3;
    int p = min(p0 + pt, Npts - 1);
    const float* xr = x + (size_t)p * XDIM + 128;
    float cc0 = xr[0], cc1 = xr[1], cc2 = xr[2];
#pragma unroll
    for (int pl = 0; pl < 3; ++pl) {
      float u = (pl == 2) ? cc1 : cc0;
      float v = (pl == 0) ? cc1 : cc2;
      float gx = fminf(fmaxf((u + 1.f) * 256.f, 0.f), 512.f);
      float gy = fminf(fmaxf((v + 1.f) * 256.f, 0.f), 512.f);
      float x0f = floorf(gx), y0f = floorf(gy);
      int x0 = (int)x0f, y0 = (int)y0f;
      int x1 = min(x0 + 1, GSZ - 1), y1 = min(y0 + 1, GSZ - 1);
      float wx = gx - x0f, wy = gy - y0f;
      float w00 = (1.f - wx) * (1.f - wy), w01 = wx * (1.f - wy);
      float w10 = (1.f - wx) * wy,        w11 = wx * wy;
      float f[8];
      if (USE_PT) {
        const unsigned short* pb = Pt + (size_t)pl * GSZ * GSZ * 32 + q * 8;
        bf16x8 v00 = *(const bf16x8*)(pb + (size_t)(y0 * GSZ + x0) * 32);
        bf16x8 v01 = *(const bf16x8*)(pb + (size_t)(y0 * GSZ + x1) * 32);
        bf16x8 v10 = *(const bf16x8*)(pb + (size_t)(y1 * GSZ + x0) * 32);
        bf16x8 v11 = *(const bf16x8*)(pb + (size_t)(y1 * GSZ + x1) * 32);
#pragma unroll
        for (int j = 0; j < 8; ++j) {
          f[j] = w00 * bf2f((unsigned short)v00[j]) + w01 * bf2f((unsigned short)v01[j])
               + w10 * bf2f((unsigned short)v10[j]) + w11 * bf2f((unsigned short)v11[j]);
        }
      } else {
#pragma unroll
        for (int j = 0; j < 8; ++j) {
          const float* pc = P + (size_t)(pl * 32 + q * 8 + j) * GSZ * GSZ;
          f[j] = w00 * pc[y0 * GSZ + x0] + w01 * pc[y0 * GSZ + x1]
               + w10 * pc[y1 * GSZ + x0] + w11 * pc[y1 * GSZ + x1];
        }
      }
      uint4 fv;
      fv.x = pk2bf(f[0], f[1]);
      fv.y = pk2bf(f[2], f[3]);
      fv.z = pk2bf(f[4], f[5]);
      fv.w = pk2bf(f[6], f[7]);
      *(uint4*)(lds + (17 + pl * 4 + q) * 1024 + slot16(pt)) = fv;
    }
  }
  __syncthreads();

  // ---- layer 0: each wave owns 2 col-groups of 64; h -> H region
#pragma unroll
  for (int gi = 0; gi < 2; ++gi) {
    const int cg = wv * 2 + gi;
    f32x4 acc[4][4];
#pragma unroll
    for (int mf = 0; mf < 4; ++mf)
#pragma unroll
      for (int nf = 0; nf < 4; ++nf) acc[mf][nf] = (f32x4){0.f, 0.f, 0.f, 0.f};
#pragma unroll
    for (int kb = 0; kb < 8; ++kb) {
      bf16x8 a[4];
      int ib = kb * 4 + lg;
      if (ib > 28) ib = 29;                         // pad k-blocks read shared zero block
#pragma unroll
      for (int mf = 0; mf < 4; ++mf)
        a[mf] = *(const bf16x8*)(lds + ib * 1024 + slot16(mf * 16 + lr));
      const unsigned short* wb = W0g + ((size_t)(kb * 4 + lg) * 256 + cg * 64 + lr) * 8;
#pragma unroll
      for (int nf = 0; nf < 4; ++nf) {
        bf16x8 b = *(const bf16x8*)(wb + nf * 128);
#pragma unroll
        for (int mf = 0; mf < 4; ++mf)
          acc[mf][nf] = __builtin_amdgcn_mfma_f32_16x16x32_bf16(a[mf], b, acc[mf][nf], 0, 0, 0);
      }
    }
#pragma unroll
    for (int nf = 0; nf < 4; ++nf) {
      int col = cg * 64 + nf * 16 + lr;
      float bs = b0[col];
      unsigned char* base = lds + H_OFF + (col >> 3) * 1024 + (col & 7) * 2;
#pragma unroll
      for (int mf = 0; mf < 4; ++mf)
#pragma unroll
        for (int reg = 0; reg < 4; ++reg) {
          int row = mf * 16 + lg * 4 + reg;
          *(unsigned short*)(base + slot16(row)) = f2bf(fmaxf(acc[mf][nf][reg] + bs, 0.f));
        }
    }
  }
  __syncthreads();

  // ---- layer 1 + direct W2 dot from accumulators (no h1 writeback)
  float part[4][4];
#pragma unroll
  for (int mf = 0; mf < 4; ++mf)
#pragma unroll
    for (int reg = 0; reg < 4; ++reg) part[mf][reg] = 0.f;

#pragma unroll
  for (int gi = 0; gi < 2; ++gi) {
    const int cg = wv * 2 + gi;
    f32x4 acc[4][4];
#pragma unroll
    for (int mf = 0; mf < 4; ++mf)
#pragma unroll
      for (int nf = 0; nf < 4; ++nf) acc[mf][nf] = (f32x4){0.f, 0.f, 0.f, 0.f};
#pragma unroll
    for (int kb = 0; kb < 8; ++kb) {
      bf16x8 a[4];
#pragma unroll
      for (int mf = 0; mf < 4; ++mf)
        a[mf] = *(const bf16x8*)(lds + H_OFF + (kb * 4 + lg) * 1024 + slot16(mf * 16 + lr));
      const unsigned short* wb = W1g + ((size_t)(kb * 4 + lg) * 256 + cg * 64 + lr) * 8;
#pragma unroll
      for (int nf = 0; nf < 4; ++nf) {
        bf16x8 b = *(const bf16x8*)(wb + nf * 128);
#pragma unroll
        for (int mf = 0; mf < 4; ++mf)
          acc[mf][nf] = __builtin_amdgcn_mfma_f32_16x16x32_bf16(a[mf], b, acc[mf][nf], 0, 0, 0);
      }
    }
#pragma unroll
    for (int nf = 0; nf < 4; ++nf) {
      int col = cg * 64 + nf * 16 + lr;
      float bs = b1[col];
      float w2v = W2[col];
#pragma unroll
      for (int mf = 0; mf < 4; ++mf)
#pragma unroll
        for (int reg = 0; reg < 4; ++reg)
          part[mf][reg] += fmaxf(acc[mf][nf][reg] + bs, 0.f) * w2v;
    }
  }
  // reduce over lr (16 lanes per lg-group hold distinct cols, same rows)
#pragma unroll
  for (int mf = 0; mf < 4; ++mf)
#pragma unroll
    for (int reg = 0; reg < 4; ++reg) {
      float v = part[mf][reg];
      v += __shfl_xor(v, 1);
      v += __shfl_xor(v, 2);
      v += __shfl_xor(v, 4);
      v += __shfl_xor(v, 8);
      part[mf][reg] = v;
    }
  if (lr == 0) {
    float* sc = (float*)(lds + SC_OFF) + wv * 64;
#pragma unroll
    for (int mf = 0; mf < 4; ++mf) {
      float4 pv;
      pv.x = part[mf][0]; pv.y = part[mf][1]; pv.z = part[mf][2]; pv.w = part[mf][3];
      *(float4*)(sc + mf * 16 + lg * 4) = pv;     // rows mf*16+lg*4+reg
    }
  }
  __syncthreads();
  if (tid < 64) {
    const float* sc = (const float*)(lds + SC_OFF);
    float s = sc[tid] + sc[64 + tid] + b2v[0];
    int p = p0 + tid;
    if (p < Npts) out[p] = s;
  }
}

extern "C" void kernel_launch(void* const* d_in, const int* in_sizes, int n_in,
                              void* d_out, int out_size, void* d_ws, size_t ws_size,
                              hipStream_t stream)
{
  const float* x  = (const float*)d_in[0];
  const float* P  = (const float*)d_in[1];
  const float* W0 = (const float*)d_in[2];
  const float* b0 = (const float*)d_in[3];
  const float* W1 = (const float*)d_in[4];
  const float* b1 = (const float*)d_in[5];
  const float* W2 = (const float*)d_in[6];
  const float* b2 = (const float*)d_in[7];
  float* out = (float*)d_out;
  int Npts = in_sizes[0] / XDIM;

  const size_t PT_BYTES = (size_t)3 * GSZ * GSZ * 32 * 2;   // ~50.5 MB
  const size_t WG_BYTES = (size_t)8192 * 8 * 2;             // 128 KB each
  char* ws = (char*)d_ws;

  int use_pt = (ws_size >= PT_BYTES + 2 * WG_BYTES) ? 1 : 0;
  unsigned short *Ptb = nullptr, *W0g, *W1g;
  if (use_pt) {
    Ptb = (unsigned short*)ws;
    W0g = (unsigned short*)(ws + PT_BYTES);
    W1g = (unsigned short*)(ws + PT_BYTES + WG_BYTES);
  } else {
    W0g = (unsigned short*)ws;
    W1g = (unsigned short*)(ws + WG_BYTES);
  }

  prep_w<<<64, 256, 0, stream>>>(W0, W1, W0g, W1g);
  if (use_pt) prep_pt<<<(3 * GSZ * GSZ + 255) / 256, 256, 0, stream>>>(P, Ptb);

  int nblk = (Npts + TROWS - 1) / TROWS;
  if (use_pt)
    sdf_tile<1><<<nblk, 128, 0, stream>>>(x, P, Ptb, W0g, W1g, b0, b1, W2, b2, out, Npts);
  else
    sdf_tile<0><<<nblk, 128, 0, stream>>>(x, P, Ptb, W0g, W1g, b0, b1, W2, b2, out, Npts);
}

// Round 10
// 331.162 us; speedup vs baseline: 2.4140x; 1.2348x over previous
//
#include <hip/hip_runtime.h>
#include <stdint.h>

#define XDIM 131
#define GSZ 513
#define TROWS 64
#define SC_OFF 32768           // 32 k-blocks * 1024 B, then 1 KB scratch

typedef __attribute__((ext_vector_type(8))) short bf16x8;
typedef __attribute__((ext_vector_type(4))) float f32x4;
typedef unsigned int uint32;

__device__ __forceinline__ unsigned short f2bf(float f) {
  uint32 u = __float_as_uint(f);
  u += 0x7fffu + ((u >> 16) & 1u);   // RTNE
  return (unsigned short)(u >> 16);
}
__device__ __forceinline__ float bf2f(unsigned short s) {
  return __uint_as_float(((uint32)s) << 16);
}
__device__ __forceinline__ uint32 pk2bf(float a, float b) {
  return (uint32)f2bf(a) | ((uint32)f2bf(b) << 16);
}
__device__ __forceinline__ int slot16(int r) { return (r * 16) ^ (((r >> 3) & 1) << 5); }

// ---------------- prep: P [3][32][513][513] f32 -> Pt [3][513][513][32] bf16
__global__ void prep_pt(const float* __restrict__ P, unsigned short* __restrict__ Pt) {
  int i = blockIdx.x * 256 + threadIdx.x;
  const int CELLS = 3 * GSZ * GSZ;
  if (i >= CELLS) return;
  int pl = i / (GSZ * GSZ);
  int yx = i - pl * (GSZ * GSZ);
  const float* src = P + (size_t)pl * 32 * GSZ * GSZ + yx;
  const size_t GG = (size_t)GSZ * GSZ;
  uint4* dst = (uint4*)(Pt + (size_t)i * 32);
#pragma unroll
  for (int w = 0; w < 4; ++w) {
    uint4 t;
    t.x = pk2bf(src[(w * 8 + 0) * GG], src[(w * 8 + 1) * GG]);
    t.y = pk2bf(src[(w * 8 + 2) * GG], src[(w * 8 + 3) * GG]);
    t.z = pk2bf(src[(w * 8 + 4) * GG], src[(w * 8 + 5) * GG]);
    t.w = pk2bf(src[(w * 8 + 6) * GG], src[(w * 8 + 7) * GG]);
    dst[w] = t;
  }
}

// ---------------- prep: W0/W1 -> bf16 MFMA B-frag order [kb][lg][n][8], W0 K-permuted
__global__ void prep_w(const float* __restrict__ W0, const float* __restrict__ W1,
                       unsigned short* __restrict__ W0g, unsigned short* __restrict__ W1g) {
  int i = blockIdx.x * 256 + threadIdx.x;  // 0..16383
  int sel = i >> 13;
  int t = i & 8191;
  int kb = t >> 10;
  int g  = (t >> 8) & 3;
  int n  = t & 255;
  float vv[8];
#pragma unroll
  for (int j = 0; j < 8; ++j) {
    int k = kb * 32 + g * 8 + j;
    float val;
    if (sel == 0) {
      int src = (k < 131) ? k : ((k >= 136 && k < 232) ? k - 5 : -1);
      val = (src >= 0) ? W0[src * 256 + n] : 0.f;
    } else {
      val = W1[k * 256 + n];
    }
    vv[j] = val;
  }
  uint4 o;
  o.x = pk2bf(vv[0], vv[1]);
  o.y = pk2bf(vv[2], vv[3]);
  o.z = pk2bf(vv[4], vv[5]);
  o.w = pk2bf(vv[6], vv[7]);
  unsigned short* dst = (sel == 0 ? W0g : W1g) + (size_t)t * 8;
  *(uint4*)dst = o;
}

// K-step-pipelined 64x64 GEMM fragment loop: wave cg owns cols [cg*64, +64).
// A and B fragments double-buffered in registers; loads of kb+1 overlap MFMAs of kb.
__device__ __forceinline__ void gemm64(const unsigned char* __restrict__ lds,
                                       const unsigned short* __restrict__ Wg,
                                       int cg, int lr, int lg, f32x4 (&acc)[4][4])
{
  bf16x8 a[4], b[4], an[4], bn[4];
  const int aoff = lg * 1024;
  const unsigned short* wrow = Wg + ((size_t)lg * 256 + cg * 64 + lr) * 8;

#pragma unroll
  for (int mf = 0; mf < 4; ++mf)
    a[mf] = *(const bf16x8*)(lds + aoff + slot16(mf * 16 + lr));
#pragma unroll
  for (int nf = 0; nf < 4; ++nf)
    b[nf] = *(const bf16x8*)(wrow + nf * 128);

#pragma unroll
  for (int kb = 0; kb < 8; ++kb) {
    if (kb < 7) {
      const unsigned char* ab = lds + (kb + 1) * 4096 + aoff;
      const unsigned short* wr = wrow + (size_t)(kb + 1) * 8192;
#pragma unroll
      for (int mf = 0; mf < 4; ++mf)
        an[mf] = *(const bf16x8*)(ab + slot16(mf * 16 + lr));
#pragma unroll
      for (int nf = 0; nf < 4; ++nf)
        bn[nf] = *(const bf16x8*)(wr + nf * 128);
    }
#pragma unroll
    for (int nf = 0; nf < 4; ++nf)
#pragma unroll
      for (int mf = 0; mf < 4; ++mf)
        acc[mf][nf] = __builtin_amdgcn_mfma_f32_16x16x32_bf16(a[mf], b[nf], acc[mf][nf], 0, 0, 0);
#pragma unroll
    for (int i = 0; i < 4; ++i) { a[i] = an[i]; b[i] = bn[i]; }
  }
}

// One 64-pt tile per 256-thread block (4 waves). In-place act->h. Fused W2 dot.
template<int USE_PT>
__global__ __launch_bounds__(256, 3) void sdf_tile(
    const float* __restrict__ x, const float* __restrict__ P,
    const unsigned short* __restrict__ Pt,
    const unsigned short* __restrict__ W0g, const unsigned short* __restrict__ W1g,
    const float* __restrict__ b0, const float* __restrict__ b1,
    const float* __restrict__ W2, const float* __restrict__ b2v,
    float* __restrict__ out, int Npts)
{
  __shared__ __align__(16) unsigned char lds[SC_OFF + 1024];

  const int tid = threadIdx.x;
  const int p0 = blockIdx.x * TROWS;
  const int lane = tid & 63, cg = tid >> 6;       // 4 waves, wave = col-group
  const int lr = lane & 15, lg = lane >> 4;

  // ---- stage x cols 0..127 -> blocks 0..15
#pragma unroll
  for (int i = 0; i < 4; ++i) {
    int t = i * 256 + tid;
    int cb = t & 15, r = t >> 4;
    int p = min(p0 + r, Npts - 1);
    const float* src = x + (size_t)p * XDIM + cb * 8;
    uint4 v;
    v.x = pk2bf(src[0], src[1]);
    v.y = pk2bf(src[2], src[3]);
    v.z = pk2bf(src[4], src[5]);
    v.w = pk2bf(src[6], src[7]);
    *(uint4*)(lds + cb * 1024 + slot16(r)) = v;
  }
  // coords block 16 (cols 128..130 + zero pad) ; zero blocks 29..31 (192 uint4)
  if (tid < 64) {
    int p = min(p0 + tid, Npts - 1);
    const float* xr = x + (size_t)p * XDIM + 128;
    uint4 v;
    v.x = pk2bf(xr[0], xr[1]);
    v.y = pk2bf(xr[2], 0.f);
    v.z = 0u; v.w = 0u;
    *(uint4*)(lds + 16 * 1024 + slot16(tid)) = v;
  } else {
    uint4 z = {0u, 0u, 0u, 0u};
    ((uint4*)(lds + 29 * 1024))[tid - 64] = z;    // 192 uint4 = blocks 29..31
  }

  // ---- fused triplane gather -> blocks 17..28 (cols 136..231); 4 thr/pt
  {
    int p_l = tid >> 2, q = tid & 3;
    int p = min(p0 + p_l, Npts - 1);
    const float* xr = x + (size_t)p * XDIM + 128;
    float cc0 = xr[0], cc1 = xr[1], cc2 = xr[2];
#pragma unroll
    for (int pl = 0; pl < 3; ++pl) {
      float u = (pl == 2) ? cc1 : cc0;
      float v = (pl == 0) ? cc1 : cc2;
      float gx = fminf(fmaxf((u + 1.f) * 256.f, 0.f), 512.f);
      float gy = fminf(fmaxf((v + 1.f) * 256.f, 0.f), 512.f);
      float x0f = floorf(gx), y0f = floorf(gy);
      int x0 = (int)x0f, y0 = (int)y0f;
      int x1 = min(x0 + 1, GSZ - 1), y1 = min(y0 + 1, GSZ - 1);
      float wx = gx - x0f, wy = gy - y0f;
      float w00 = (1.f - wx) * (1.f - wy), w01 = wx * (1.f - wy);
      float w10 = (1.f - wx) * wy,        w11 = wx * wy;
      float f[8];
      if (USE_PT) {
        const unsigned short* pb = Pt + (size_t)pl * GSZ * GSZ * 32 + q * 8;
        bf16x8 v00 = *(const bf16x8*)(pb + (size_t)(y0 * GSZ + x0) * 32);
        bf16x8 v01 = *(const bf16x8*)(pb + (size_t)(y0 * GSZ + x1) * 32);
        bf16x8 v10 = *(const bf16x8*)(pb + (size_t)(y1 * GSZ + x0) * 32);
        bf16x8 v11 = *(const bf16x8*)(pb + (size_t)(y1 * GSZ + x1) * 32);
#pragma unroll
        for (int j = 0; j < 8; ++j) {
          f[j] = w00 * bf2f((unsigned short)v00[j]) + w01 * bf2f((unsigned short)v01[j])
               + w10 * bf2f((unsigned short)v10[j]) + w11 * bf2f((unsigned short)v11[j]);
        }
      } else {
#pragma unroll
        for (int j = 0; j < 8; ++j) {
          const float* pc = P + (size_t)(pl * 32 + q * 8 + j) * GSZ * GSZ;
          f[j] = w00 * pc[y0 * GSZ + x0] + w01 * pc[y0 * GSZ + x1]
               + w10 * pc[y1 * GSZ + x0] + w11 * pc[y1 * GSZ + x1];
        }
      }
      uint4 fv;
      fv.x = pk2bf(f[0], f[1]);
      fv.y = pk2bf(f[2], f[3]);
      fv.z = pk2bf(f[4], f[5]);
      fv.w = pk2bf(f[6], f[7]);
      *(uint4*)(lds + (17 + pl * 4 + q) * 1024 + slot16(p_l)) = fv;
    }
  }
  __syncthreads();

  // ---- layer 0 (K=256 padded; pipelined)
  {
    f32x4 acc[4][4];
#pragma unroll
    for (int mf = 0; mf < 4; ++mf)
#pragma unroll
      for (int nf = 0; nf < 4; ++nf) acc[mf][nf] = (f32x4){0.f, 0.f, 0.f, 0.f};
    gemm64(lds, W0g, cg, lr, lg, acc);
    __syncthreads();               // all A-reads of act done before overwrite with h
#pragma unroll
    for (int nf = 0; nf < 4; ++nf) {
      int col = cg * 64 + nf * 16 + lr;
      float bs = b0[col];
      unsigned char* base = lds + (col >> 3) * 1024 + (col & 7) * 2;
#pragma unroll
      for (int mf = 0; mf < 4; ++mf)
#pragma unroll
        for (int reg = 0; reg < 4; ++reg) {
          int row = mf * 16 + lg * 4 + reg;
          *(unsigned short*)(base + slot16(row)) = f2bf(fmaxf(acc[mf][nf][reg] + bs, 0.f));
        }
    }
  }
  __syncthreads();

  // ---- layer 1 (pipelined) + fused W2 dot from accumulators (no h1 writeback)
  {
    f32x4 acc[4][4];
#pragma unroll
    for (int mf = 0; mf < 4; ++mf)
#pragma unroll
      for (int nf = 0; nf < 4; ++nf) acc[mf][nf] = (f32x4){0.f, 0.f, 0.f, 0.f};
    gemm64(lds, W1g, cg, lr, lg, acc);

    float part[4][4];
#pragma unroll
    for (int mf = 0; mf < 4; ++mf)
#pragma unroll
      for (int reg = 0; reg < 4; ++reg) part[mf][reg] = 0.f;
#pragma unroll
    for (int nf = 0; nf < 4; ++nf) {
      int col = cg * 64 + nf * 16 + lr;
      float bs = b1[col];
      float w2v = W2[col];
#pragma unroll
      for (int mf = 0; mf < 4; ++mf)
#pragma unroll
        for (int reg = 0; reg < 4; ++reg)
          part[mf][reg] += fmaxf(acc[mf][nf][reg] + bs, 0.f) * w2v;
    }
    // reduce over lr (low 4 lane bits)
#pragma unroll
    for (int mf = 0; mf < 4; ++mf)
#pragma unroll
      for (int reg = 0; reg < 4; ++reg) {
        float v = part[mf][reg];
        v += __shfl_xor(v, 1);
        v += __shfl_xor(v, 2);
        v += __shfl_xor(v, 4);
        v += __shfl_xor(v, 8);
        part[mf][reg] = v;
      }
    if (lr == 0) {
      float* sc = (float*)(lds + SC_OFF) + cg * 64;
#pragma unroll
      for (int mf = 0; mf < 4; ++mf) {
        float4 pv;
        pv.x = part[mf][0]; pv.y = part[mf][1]; pv.z = part[mf][2]; pv.w = part[mf][3];
        *(float4*)(sc + mf * 16 + lg * 4) = pv;   // row = mf*16+lg*4+reg
      }
    }
  }
  __syncthreads();
  if (tid < 64) {
    const float* sc = (const float*)(lds + SC_OFF);
    float s = sc[tid] + sc[64 + tid] + sc[128 + tid] + sc[192 + tid] + b2v[0];
    int p = p0 + tid;
    if (p < Npts) out[p] = s;
  }
}

extern "C" void kernel_launch(void* const* d_in, const int* in_sizes, int n_in,
                              void* d_out, int out_size, void* d_ws, size_t ws_size,
                              hipStream_t stream)
{
  const float* x  = (const float*)d_in[0];
  const float* P  = (const float*)d_in[1];
  const float* W0 = (const float*)d_in[2];
  const float* b0 = (const float*)d_in[3];
  const float* W1 = (const float*)d_in[4];
  const float* b1 = (const float*)d_in[5];
  const float* W2 = (const float*)d_in[6];
  const float* b2 = (const float*)d_in[7];
  float* out = (float*)d_out;
  int Npts = in_sizes[0] / XDIM;

  const size_t PT_BYTES = (size_t)3 * GSZ * GSZ * 32 * 2;   // ~50.5 MB
  const size_t WG_BYTES = (size_t)8192 * 8 * 2;             // 128 KB each
  char* ws = (char*)d_ws;

  int use_pt = (ws_size >= PT_BYTES + 2 * WG_BYTES) ? 1 : 0;
  unsigned short *Ptb = nullptr, *W0g, *W1g;
  if (use_pt) {
    Ptb = (unsigned short*)ws;
    W0g = (unsigned short*)(ws + PT_BYTES);
    W1g = (unsigned short*)(ws + PT_BYTES + WG_BYTES);
  } else {
    W0g = (unsigned short*)ws;
    W1g = (unsigned short*)(ws + WG_BYTES);
  }

  prep_w<<<64, 256, 0, stream>>>(W0, W1, W0g, W1g);
  if (use_pt) prep_pt<<<(3 * GSZ * GSZ + 255) / 256, 256, 0, stream>>>(P, Ptb);

  int nblk = (Npts + TROWS - 1) / TROWS;
  if (use_pt)
    sdf_tile<1><<<nblk, 256, 0, stream>>>(x, P, Ptb, W0g, W1g, b0, b1, W2, b2, out, Npts);
  else
    sdf_tile<0><<<nblk, 256, 0, stream>>>(x, P, Ptb, W0g, W1g, b0, b1, W2, b2, out, Npts);
}